// Round 19
// baseline (359.985 us; speedup 1.0000x reference)
//
#include <hip/hip_runtime.h>
#include <stdint.h>

typedef __attribute__((ext_vector_type(4))) float f32x4;
typedef __attribute__((ext_vector_type(16))) float f32x16;
typedef __attribute__((ext_vector_type(8))) short bf16x8;
typedef unsigned short u16;

#define MFMA(a, b, c) __builtin_amdgcn_mfma_f32_16x16x32_bf16(a, b, c, 0, 0, 0)
#define MFMA32(a, b, c) __builtin_amdgcn_mfma_f32_32x32x16_bf16(a, b, c, 0, 0, 0)
#define EXP2(x) __builtin_amdgcn_exp2f(x)
#define FENCE asm volatile("" ::: "memory")
#define BARRIER do { FENCE; __builtin_amdgcn_s_barrier(); FENCE; } while (0)

__device__ __forceinline__ u16 f2bf(float f) {
  union { float f; unsigned u; } x; x.f = f;
  unsigned r = x.u + 0x7fffu + ((x.u >> 16) & 1u);
  return (u16)(r >> 16);
}

__device__ __forceinline__ unsigned cvtpk(float lo, float hi) {
  unsigned r;
  asm("v_cvt_pk_bf16_f32 %0, %1, %2" : "=v"(r) : "v"(lo), "v"(hi));
  return r;
}

__device__ __forceinline__ void pl32swap(unsigned& a, unsigned& b) {
  asm volatile("v_permlane32_swap_b32 %0, %1" : "+v"(a), "+v"(b));
}

__device__ __forceinline__ void gload16(const void* g, void* l) {
  __builtin_amdgcn_global_load_lds(
      (const __attribute__((address_space(1))) unsigned int*)g,
      (__attribute__((address_space(3))) unsigned int*)l, 16, 0, 0);
}

// ---------------------------------------------------------------- fused f32->bf16 casts
__global__ void __launch_bounds__(256)
cast_all(const float* __restrict__ x, const float* __restrict__ wq,
         const float* __restrict__ wo, u16* __restrict__ xb,
         u16* __restrict__ wqb, u16* __restrict__ wob) {
  for (int idx = blockIdx.x * 256 + threadIdx.x; idx < 6291456; idx += 256 * 2048) {
    const float* in;
    u16* out;
    int j;
    if (idx < 2097152) { in = x; out = xb; j = idx; }
    else if (idx < 5242880) { in = wq; out = wqb; j = idx - 2097152; }
    else { in = wo; out = wob; j = idx - 5242880; }
    float4 v = reinterpret_cast<const float4*>(in)[j];
    ushort4 o;
    o.x = f2bf(v.x); o.y = f2bf(v.y); o.z = f2bf(v.z); o.w = f2bf(v.w);
    reinterpret_cast<ushort4*>(out)[j] = o;
  }
}

// ---------------------------------------------------------------- 4-phase GEMM, BM=128 x BN=256 (R17)
template <int EPI>
__global__ void __launch_bounds__(512)
gemm8(const u16* __restrict__ A, const u16* __restrict__ B,
      void* __restrict__ C0, void* __restrict__ C1, void* __restrict__ C2,
      int M, int N, int K, int MBt) {
  __shared__ alignas(16) char smb[98304];
  const int tid = threadIdx.x;
  const int w = tid >> 6, lane = tid & 63;
  const int lr = lane & 15, g = lane >> 4;
  const int wm = w >> 2, wn = w & 3;
  const int gb = (blockIdx.x & 7) * ((int)gridDim.x >> 3) + (blockIdx.x >> 3);
  const int mb = gb % MBt, nb = gb / MBt;
  const int m0 = mb * 128, n0 = nb * 256;
  const int NT = K >> 6, NIT = NT >> 1;

  const int l8 = lane >> 3, l7 = lane & 7;
  const int csb = (l7 ^ l8) * 16;
  const char* asrc;
  unsigned adst;
  {
    int r = (w & 3) * 8 + ((w >> 2) << 6) + l8;
    asrc = (const char*)(A + (size_t)(m0 + r) * K) + csb;
    adst = (unsigned)(r * 128 + l7 * 16);
  }
  const char* bsrcb[2];
  unsigned bdst[2];
#pragma unroll
  for (int j = 0; j < 2; ++j) {
    int c = 2 * w + j;
    int r = (c & 3) * 8 + ((c >> 2) << 6) + l8;
    bsrcb[j] = (const char*)(B + (size_t)(n0 + r) * K) + csb;
    bdst[j] = (unsigned)(r * 128 + l7 * 16);
  }
  const size_t row32 = (size_t)32 * K * 2;

#define STG(kt, u)                                                               \
  do {                                                                           \
    if ((kt) < NT) {                                                             \
      size_t _ko = (size_t)(kt) * 128;                                           \
      int _da = ((kt) & 1) ? 16384 : 0;                                          \
      int _db = 32768 + (((kt) & 1) ? 32768 : 0);                                \
      if ((u) == 0) {                                                            \
        gload16(asrc + _ko, smb + _da + adst);                                   \
      } else if ((u) == 1) {                                                     \
        gload16(bsrcb[0] + _ko, smb + _db + bdst[0]);                            \
        gload16(bsrcb[1] + _ko, smb + _db + bdst[1]);                            \
      } else if ((u) == 2) {                                                     \
        gload16(asrc + row32 + _ko, smb + _da + 4096 + adst);                    \
      } else {                                                                   \
        gload16(bsrcb[0] + row32 + _ko, smb + _db + 4096 + bdst[0]);             \
        gload16(bsrcb[1] + row32 + _ko, smb + _db + 4096 + bdst[1]);             \
      }                                                                          \
    }                                                                            \
  } while (0)
#define VMC(n) asm volatile("s_waitcnt vmcnt(" #n ")" ::: "memory")

  f32x4 acc[4][4];
#pragma unroll
  for (int x = 0; x < 4; ++x)
#pragma unroll
    for (int y = 0; y < 4; ++y) acc[x][y] = f32x4{0.f, 0.f, 0.f, 0.f};
  bf16x8 af[2][2], bf01[2][2], bf23[2][2];
  const int aoff0 = ((g) ^ (lr & 7)) << 4;
  const int aoff1 = ((4 + g) ^ (lr & 7)) << 4;
  const int arowb = (wm * 64 + lr) * 128;
  const int browb = (wn * 64 + lr) * 128;

  auto LDA = [&](const char* base, int mih) {
#pragma unroll
    for (int mi = 0; mi < 2; ++mi) {
      const char* p = base + arowb + (mih * 32 + mi * 16) * 128;
      af[mi][0] = *(const bf16x8*)(p + aoff0);
      af[mi][1] = *(const bf16x8*)(p + aoff1);
    }
  };
  auto LDB = [&](const char* base, bf16x8 (*bfr)[2], int nih) {
#pragma unroll
    for (int ni = 0; ni < 2; ++ni) {
      const char* p = base + browb + (nih * 32 + ni * 16) * 128;
      bfr[ni][0] = *(const bf16x8*)(p + aoff0);
      bfr[ni][1] = *(const bf16x8*)(p + aoff1);
    }
  };
  auto MM = [&](int mih, int nih, bf16x8 (*bfr)[2]) {
#pragma unroll
    for (int mi = 0; mi < 2; ++mi)
#pragma unroll
      for (int ni = 0; ni < 2; ++ni) {
        acc[mih * 2 + mi][nih * 2 + ni] =
            MFMA(af[mi][0], bfr[ni][0], acc[mih * 2 + mi][nih * 2 + ni]);
        acc[mih * 2 + mi][nih * 2 + ni] =
            MFMA(af[mi][1], bfr[ni][1], acc[mih * 2 + mi][nih * 2 + ni]);
      }
  };

  STG(0, 0); STG(0, 1); STG(0, 2); STG(0, 3);
  STG(1, 0); STG(1, 1); STG(1, 3);
  VMC(5);
  BARRIER;

  const char* A0 = smb;
  const char* A1 = smb + 16384;
  const char* B0 = smb + 32768;
  const char* B1 = smb + 65536;

  for (int it = 0; it < NIT; ++it) {
    const int t0 = 2 * it;
    const bool last = (it == NIT - 1);
    LDA(A0, 0); LDB(B0, bf01, 0); LDB(B0, bf23, 1);
    STG(t0 + 1, 2);
    VMC(6);
    BARRIER;
    __builtin_amdgcn_s_setprio(1); MM(0, 0, bf01); MM(0, 1, bf23); __builtin_amdgcn_s_setprio(0);
    BARRIER;
    LDA(A0, 1);
    STG(t0 + 2, 0); STG(t0 + 2, 1); STG(t0 + 2, 3);
    if (last) VMC(1); else VMC(6);
    BARRIER;
    __builtin_amdgcn_s_setprio(1); MM(1, 1, bf23); MM(1, 0, bf01); __builtin_amdgcn_s_setprio(0);
    BARRIER;
    LDA(A1, 0); LDB(B1, bf01, 0); LDB(B1, bf23, 1);
    STG(t0 + 2, 2);
    if (last) VMC(0); else VMC(6);
    BARRIER;
    __builtin_amdgcn_s_setprio(1); MM(0, 0, bf01); MM(0, 1, bf23); __builtin_amdgcn_s_setprio(0);
    BARRIER;
    LDA(A1, 1);
    STG(t0 + 3, 0); STG(t0 + 3, 1); STG(t0 + 3, 3);
    if (last) VMC(0); else VMC(6);
    BARRIER;
    __builtin_amdgcn_s_setprio(1); MM(1, 1, bf23); MM(1, 0, bf01); __builtin_amdgcn_s_setprio(0);
    BARRIER;
  }
#undef STG
#undef VMC

  if (EPI == 0) {
    const float qs = 0.08838834764831845f * 1.4426950408889634f;
    u16* qo = (u16*)C0;
    u16* ko = (u16*)C1;
    u16* vo = (u16*)C2;
#pragma unroll
    for (int a = 0; a < 4; ++a) {
      int s0 = m0 + wm * 64 + a * 16 + g * 4;
#pragma unroll
      for (int b = 0; b < 4; ++b) {
        int n = n0 + wn * 64 + b * 16 + lr;
        int t = n >> 11, hh = (n >> 7) & 15, d = n & 127;
        if (t == 2) {
          ushort4 pk;
          pk.x = f2bf(acc[a][b][0]);
          pk.y = f2bf(acc[a][b][1]);
          pk.z = f2bf(acc[a][b][2]);
          pk.w = f2bf(acc[a][b][3]);
          *(ushort4*)(vo + (size_t)(hh * 128 + d) * 4096 + s0) = pk;
        } else {
          float sc = (t == 0) ? qs : 1.f;
          u16* dq = (t == 0 ? qo : ko) + (size_t)(hh * 4096 + s0) * 128 + d;
#pragma unroll
          for (int j = 0; j < 4; ++j) dq[(size_t)j * 128] = f2bf(acc[a][b][j] * sc);
        }
      }
    }
  } else {
    float* C = (float*)C0;
#pragma unroll
    for (int a = 0; a < 4; ++a)
#pragma unroll
      for (int b = 0; b < 4; ++b) {
        size_t r0 = (size_t)(m0 + wm * 64 + a * 16 + g * 4);
        int cn = n0 + wn * 64 + b * 16 + lr;
#pragma unroll
        for (int j = 0; j < 4; ++j) C[(r0 + j) * N + cn] = acc[a][b][j];
      }
  }
}

// ---------------------------------------------------------------- flash attention
// Split-KV 2-way, KVBLK=64/group, SINGLE-buffer staging (m97 pattern): 8 waves /
// 512 thr; waves 0-3 compute kv[0,2048), waves 4-7 kv[2048,4096); wave (w&3)
// owns 32 q of the same 128-q block. Grid 512 = 2 blocks/CU = 4 waves/SIMD
// (TLP 2x vs R14) at SAME 32-iteration count as R14 (fixed costs equal — fixes
// R13's regression). Staging latency covered by the co-resident block (R3/m114:
// dbuf was worth 0 at 2 blocks/CU). LDS 66KB: Kg0@0, Kg1@16K, Vg0@32K, Vg1@48K
// (single buf, 2 barriers/iter); merge region reuses it after final barrier.
// K [64][256B] 4-bit-XOR (R12); V pair-row [64][256B] (R10); softmax/paf (R12);
// merge math (R13-proven). VGPR ~116 <= 128 cap for 4 waves/SIMD.
__global__ void __launch_bounds__(512)
attn_kernel(const u16* __restrict__ qg, const u16* __restrict__ kg,
            const u16* __restrict__ vtg, u16* __restrict__ og) {
  __shared__ alignas(64) char smb[67584];
  const int tid = threadIdx.x;
  const int w = tid >> 6, lane = tid & 63;
  const int ql = lane & 31, hl = lane >> 5;
  const int gb = (blockIdx.x & 7) * 64 + (blockIdx.x >> 3);  // XCD swizzle (512=8*64)
  const int h = gb >> 5;
  const int qb = gb & 31;     // 128-q block
  const int g2 = w >> 2;      // compute kv-half
  const int qw = w & 3;       // q chunk (32 rows)

  // staging: wave pair (w>>1) -> unit u: 0=Kg0 1=Vg0 2=Kg1 3=Vg1; chunk (w&1)*8+i
  const u16* ssrc[8];
  unsigned sdst[8];
  size_t sstep;
  {
    const int u = w >> 1;
    const int sg = u >> 1;
    if (!(u & 1)) {  // K: tile [64 rows][256B], 4-bit XOR
      sstep = 64 * 128;
#pragma unroll
      for (int i = 0; i < 8; ++i) {
        int c = (w & 1) * 8 + i;
        int r = c * 4 + (lane >> 4);          // kv row 0..63
        int sb = (lane & 15) ^ (r & 15);
        ssrc[i] = kg + (size_t)(h * 4096 + sg * 2048 + r) * 128 + sb * 8;
        sdst[i] = sg * 16384 + c * 1024;
      }
    } else {         // V: pair-row tile [64][256B] (row j = d-rows 2j,2j+1)
      sstep = 64;
#pragma unroll
      for (int i = 0; i < 8; ++i) {
        int c = (w & 1) * 8 + i;
        int j = c * 4 + (lane >> 4);          // pair-row 0..63
        int x = (lane & 15) ^ (j & 15);
        int e = x >> 3, b = x & 7;
        ssrc[i] = vtg + (size_t)(h * 128 + 2 * j + e) * 4096 + sg * 2048 + b * 8;
        sdst[i] = 32768 + sg * 16384 + c * 1024;
      }
    }
  }

  // Q fragments (pre-scaled by scale*log2e)
  const u16* qrow = qg + (size_t)(h * 4096 + qb * 128 + qw * 32 + ql) * 128 + hl * 8;
  bf16x8 qf[8];
#pragma unroll
  for (int s = 0; s < 8; ++s) qf[s] = *(const bf16x8*)(qrow + s * 16);

  f32x16 of[4];
#pragma unroll
  for (int i = 0; i < 4; ++i)
#pragma unroll
    for (int r = 0; r < 16; ++r) of[i][r] = 0.f;
  float mrun = -1e30f, lsum = 0.f;
  const float thr = 6.0f;

  const int kxor = (ql & 15) << 4;
  const char* kbuf = smb + g2 * 16384;
  const char* vbuf = smb + 32768 + g2 * 16384;
  const int vj = ql >> 1;
  const int ve8 = (ql & 1) << 3;

  // prologue: stage tile 0
#pragma unroll
  for (int i = 0; i < 8; ++i) gload16(ssrc[i], smb + sdst[i]);
  asm volatile("s_waitcnt vmcnt(0)" ::: "memory");
  BARRIER;

  for (int t = 0; t < 32; ++t) {
    // ---- compute tile t (single buffer)
    f32x16 st0, st1;
#pragma unroll
    for (int r = 0; r < 16; ++r) { st0[r] = 0.f; st1[r] = 0.f; }
    __builtin_amdgcn_s_setprio(1);
#pragma unroll
    for (int s = 0; s < 8; ++s) {
      int off = ((s * 2 + hl) << 4) ^ kxor;
      bf16x8 k0 = *(const bf16x8*)(kbuf + ql * 256 + off);
      bf16x8 k1 = *(const bf16x8*)(kbuf + (32 + ql) * 256 + off);
      st0 = MFMA32(k0, qf[s], st0);
      st1 = MFMA32(k1, qf[s], st1);
    }
    __builtin_amdgcn_s_setprio(0);

    float tmax = -1e30f;
#pragma unroll
    for (int r = 0; r < 16; ++r) tmax = fmaxf(tmax, fmaxf(st0[r], st1[r]));
    tmax = fmaxf(tmax, __shfl_xor(tmax, 32));
    if (!__all(tmax - mrun <= thr)) {  // defer-max
      float mnew = fmaxf(mrun, tmax);
      float esc = EXP2(mrun - mnew);
#pragma unroll
      for (int db = 0; db < 4; ++db)
#pragma unroll
        for (int r = 0; r < 16; ++r) of[db][r] *= esc;
      lsum *= esc;
      mrun = mnew;
    }
    float psum = 0.f;
    unsigned pk0[8], pk1[8];
#pragma unroll
    for (int i = 0; i < 8; ++i) {
      float a0 = EXP2(st0[2 * i] - mrun);
      float b0 = EXP2(st0[2 * i + 1] - mrun);
      float a1 = EXP2(st1[2 * i] - mrun);
      float b1 = EXP2(st1[2 * i + 1] - mrun);
      psum += (a0 + b0) + (a1 + b1);
      pk0[i] = cvtpk(a0, b0);
      pk1[i] = cvtpk(a1, b1);
    }
    psum += __shfl_xor(psum, 32);
    lsum += psum;

    pl32swap(pk0[0], pk0[2]); pl32swap(pk0[1], pk0[3]);
    pl32swap(pk0[4], pk0[6]); pl32swap(pk0[5], pk0[7]);
    pl32swap(pk1[0], pk1[2]); pl32swap(pk1[1], pk1[3]);
    pl32swap(pk1[4], pk1[6]); pl32swap(pk1[5], pk1[7]);
    union U { unsigned u[4]; bf16x8 v; };
    U paf[4];
#pragma unroll
    for (int i = 0; i < 4; ++i) { paf[0].u[i] = pk0[i]; paf[1].u[i] = pk0[4 + i]; }
#pragma unroll
    for (int i = 0; i < 4; ++i) { paf[2].u[i] = pk1[i]; paf[3].u[i] = pk1[4 + i]; }

    // O^T += Vt * P^T (pair-row V)
    __builtin_amdgcn_s_setprio(1);
#pragma unroll
    for (int db = 0; db < 4; ++db) {
      int j = db * 16 + vj;
      const char* vrow = vbuf + j * 256;
#pragma unroll
      for (int kp = 0; kp < 4; ++kp) {
        int m = (ve8 | (kp * 2 + hl)) ^ (j & 15);
        bf16x8 vf = *(const bf16x8*)(vrow + m * 16);
        of[db] = MFMA32(vf, paf[kp].v, of[db]);
      }
    }
    __builtin_amdgcn_s_setprio(0);

    // ---- all waves done reading tile t; stage t+1 over it
    BARRIER;
    if (t + 1 < 32) {
#pragma unroll
      for (int i = 0; i < 8; ++i)
        gload16(ssrc[i] + (size_t)(t + 1) * sstep, smb + sdst[i]);
      asm volatile("s_waitcnt vmcnt(0)" ::: "memory");
    }
    BARRIER;
  }

  // ---- split-KV merge (R13-proven): waves 4-7 publish; waves 0-3 combine & store
  __syncthreads();
  if (w >= 4) {
    char* base = smb + qw * 16384 + lane * 256;
#pragma unroll
    for (int db = 0; db < 4; ++db) *(f32x16*)(base + db * 64) = of[db];
    float2 ml;
    ml.x = mrun; ml.y = lsum;
    *(float2*)(smb + 65536 + (qw * 64 + lane) * 8) = ml;
  }
  __syncthreads();
  if (w < 4) {
    const char* base = smb + qw * 16384 + lane * 256;
    float2 ml = *(const float2*)(smb + 65536 + (qw * 64 + lane) * 8);
    float m = fmaxf(mrun, ml.x);
    float a0 = EXP2(mrun - m);
    float a1 = EXP2(ml.x - m);
    float l = lsum * a0 + ml.y * a1;
    float linv = 1.f / (l + 1e-8f);
    float fa0 = a0 * linv, fa1 = a1 * linv;
    size_t qrow_o = (size_t)(qb * 128 + qw * 32 + ql) * 2048 + h * 128;
#pragma unroll
    for (int db = 0; db < 4; ++db) {
      f32x16 ob = *(const f32x16*)(base + db * 64);
#pragma unroll
      for (int u = 0; u < 4; ++u) {
        ushort4 pk;
        pk.x = f2bf(of[db][4 * u + 0] * fa0 + ob[4 * u + 0] * fa1);
        pk.y = f2bf(of[db][4 * u + 1] * fa0 + ob[4 * u + 1] * fa1);
        pk.z = f2bf(of[db][4 * u + 2] * fa0 + ob[4 * u + 2] * fa1);
        pk.w = f2bf(of[db][4 * u + 3] * fa0 + ob[4 * u + 3] * fa1);
        *(ushort4*)(og + qrow_o + db * 32 + 8 * u + hl * 4) = pk;
      }
    }
  }
}

// ---------------------------------------------------------------- launcher
extern "C" void kernel_launch(void* const* d_in, const int* in_sizes, int n_in,
                              void* d_out, int out_size, void* d_ws, size_t ws_size,
                              hipStream_t stream) {
  const float* x = (const float*)d_in[0];      // [4096][2048]
  const float* w_qkv = (const float*)d_in[1];  // [6144][2048]
  const float* w_out = (const float*)d_in[2];  // [2048][2048]

  char* ws = (char*)d_ws;
  u16* xb = (u16*)(ws + 0);            // 16 MB
  u16* wqkvb = (u16*)(ws + 16777216);  // 24 MB
  u16* woutb = (u16*)(ws + 41943040);  // 8 MB
  u16* qb = (u16*)(ws + 50331648);     // 16 MB  [NH][S][HD] (pre-scaled)
  u16* kb = (u16*)(ws + 67108864);     // 16 MB  [NH][S][HD]
  u16* vtb = (u16*)(ws + 83886080);    // 16 MB  [NH][HD][S]
  u16* aob = (u16*)(ws + 100663296);   // 16 MB  [S][H]

  cast_all<<<2048, 256, 0, stream>>>(x, w_qkv, w_out, xb, wqkvb, woutb);
  gemm8<0><<<768, 512, 0, stream>>>(xb, wqkvb, qb, kb, vtb, 4096, 6144, 2048, 32);
  attn_kernel<<<512, 512, 0, stream>>>(qb, kb, vtb, aob);
  gemm8<1><<<256, 512, 0, stream>>>(aob, woutb, d_out, nullptr, nullptr, 4096, 2048, 2048, 32);
}

// Round 21
// 312.924 us; speedup vs baseline: 1.1504x; 1.1504x over previous
//
#include <hip/hip_runtime.h>
#include <stdint.h>

typedef __attribute__((ext_vector_type(4))) float f32x4;
typedef __attribute__((ext_vector_type(16))) float f32x16;
typedef __attribute__((ext_vector_type(8))) short bf16x8;
typedef unsigned short u16;

#define MFMA(a, b, c) __builtin_amdgcn_mfma_f32_16x16x32_bf16(a, b, c, 0, 0, 0)
#define MFMA32(a, b, c) __builtin_amdgcn_mfma_f32_32x32x16_bf16(a, b, c, 0, 0, 0)
#define EXP2(x) __builtin_amdgcn_exp2f(x)
#define FENCE asm volatile("" ::: "memory")
#define BARRIER do { FENCE; __builtin_amdgcn_s_barrier(); FENCE; } while (0)

__device__ __forceinline__ u16 f2bf(float f) {
  union { float f; unsigned u; } x; x.f = f;
  unsigned r = x.u + 0x7fffu + ((x.u >> 16) & 1u);
  return (u16)(r >> 16);
}

__device__ __forceinline__ unsigned cvtpk(float lo, float hi) {
  unsigned r;
  asm("v_cvt_pk_bf16_f32 %0, %1, %2" : "=v"(r) : "v"(lo), "v"(hi));
  return r;
}

__device__ __forceinline__ void pl32swap(unsigned& a, unsigned& b) {
  asm volatile("v_permlane32_swap_b32 %0, %1" : "+v"(a), "+v"(b));
}

__device__ __forceinline__ void gload16(const void* g, void* l) {
  __builtin_amdgcn_global_load_lds(
      (const __attribute__((address_space(1))) unsigned int*)g,
      (__attribute__((address_space(3))) unsigned int*)l, 16, 0, 0);
}

// ---------------------------------------------------------------- fused f32->bf16 casts
// one float4 per thread. Total float4 groups = (8388608+12582912+4194304)/4 = 6291456.
// Splits IN FLOAT4 UNITS: x 2097152, wqkv 3145728 (cum 5242880), wout 1048576.
// grid 24576 x 256 = 6291456 threads exactly.
__global__ void __launch_bounds__(256)
cast_all(const float* __restrict__ x, const float* __restrict__ wq,
         const float* __restrict__ wo, u16* __restrict__ xb,
         u16* __restrict__ wqb, u16* __restrict__ wob) {
  int idx = blockIdx.x * 256 + threadIdx.x;  // float4 index, 0..6291455
  const float* in;
  u16* out;
  int j;
  if (idx < 2097152) { in = x; out = xb; j = idx; }
  else if (idx < 5242880) { in = wq; out = wqb; j = idx - 2097152; }
  else { in = wo; out = wob; j = idx - 5242880; }
  float4 v = reinterpret_cast<const float4*>(in)[j];
  ushort4 o;
  o.x = f2bf(v.x); o.y = f2bf(v.y); o.z = f2bf(v.z); o.w = f2bf(v.w);
  reinterpret_cast<ushort4*>(out)[j] = o;
}

// ---------------------------------------------------------------- 4-phase GEMM, BM=128 x BN=256 (R17, proven)
template <int EPI>
__global__ void __launch_bounds__(512)
gemm8(const u16* __restrict__ A, const u16* __restrict__ B,
      void* __restrict__ C0, void* __restrict__ C1, void* __restrict__ C2,
      int M, int N, int K, int MBt) {
  __shared__ alignas(16) char smb[98304];
  const int tid = threadIdx.x;
  const int w = tid >> 6, lane = tid & 63;
  const int lr = lane & 15, g = lane >> 4;
  const int wm = w >> 2, wn = w & 3;
  const int gb = (blockIdx.x & 7) * ((int)gridDim.x >> 3) + (blockIdx.x >> 3);
  const int mb = gb % MBt, nb = gb / MBt;
  const int m0 = mb * 128, n0 = nb * 256;
  const int NT = K >> 6, NIT = NT >> 1;

  const int l8 = lane >> 3, l7 = lane & 7;
  const int csb = (l7 ^ l8) * 16;
  const char* asrc;
  unsigned adst;
  {
    int r = (w & 3) * 8 + ((w >> 2) << 6) + l8;
    asrc = (const char*)(A + (size_t)(m0 + r) * K) + csb;
    adst = (unsigned)(r * 128 + l7 * 16);
  }
  const char* bsrcb[2];
  unsigned bdst[2];
#pragma unroll
  for (int j = 0; j < 2; ++j) {
    int c = 2 * w + j;
    int r = (c & 3) * 8 + ((c >> 2) << 6) + l8;
    bsrcb[j] = (const char*)(B + (size_t)(n0 + r) * K) + csb;
    bdst[j] = (unsigned)(r * 128 + l7 * 16);
  }
  const size_t row32 = (size_t)32 * K * 2;

#define STG(kt, u)                                                               \
  do {                                                                           \
    if ((kt) < NT) {                                                             \
      size_t _ko = (size_t)(kt) * 128;                                           \
      int _da = ((kt) & 1) ? 16384 : 0;                                          \
      int _db = 32768 + (((kt) & 1) ? 32768 : 0);                                \
      if ((u) == 0) {                                                            \
        gload16(asrc + _ko, smb + _da + adst);                                   \
      } else if ((u) == 1) {                                                     \
        gload16(bsrcb[0] + _ko, smb + _db + bdst[0]);                            \
        gload16(bsrcb[1] + _ko, smb + _db + bdst[1]);                            \
      } else if ((u) == 2) {                                                     \
        gload16(asrc + row32 + _ko, smb + _da + 4096 + adst);                    \
      } else {                                                                   \
        gload16(bsrcb[0] + row32 + _ko, smb + _db + 4096 + bdst[0]);             \
        gload16(bsrcb[1] + row32 + _ko, smb + _db + 4096 + bdst[1]);             \
      }                                                                          \
    }                                                                            \
  } while (0)
#define VMC(n) asm volatile("s_waitcnt vmcnt(" #n ")" ::: "memory")

  f32x4 acc[4][4];
#pragma unroll
  for (int x = 0; x < 4; ++x)
#pragma unroll
    for (int y = 0; y < 4; ++y) acc[x][y] = f32x4{0.f, 0.f, 0.f, 0.f};
  bf16x8 af[2][2], bf01[2][2], bf23[2][2];
  const int aoff0 = ((g) ^ (lr & 7)) << 4;
  const int aoff1 = ((4 + g) ^ (lr & 7)) << 4;
  const int arowb = (wm * 64 + lr) * 128;
  const int browb = (wn * 64 + lr) * 128;

  auto LDA = [&](const char* base, int mih) {
#pragma unroll
    for (int mi = 0; mi < 2; ++mi) {
      const char* p = base + arowb + (mih * 32 + mi * 16) * 128;
      af[mi][0] = *(const bf16x8*)(p + aoff0);
      af[mi][1] = *(const bf16x8*)(p + aoff1);
    }
  };
  auto LDB = [&](const char* base, bf16x8 (*bfr)[2], int nih) {
#pragma unroll
    for (int ni = 0; ni < 2; ++ni) {
      const char* p = base + browb + (nih * 32 + ni * 16) * 128;
      bfr[ni][0] = *(const bf16x8*)(p + aoff0);
      bfr[ni][1] = *(const bf16x8*)(p + aoff1);
    }
  };
  auto MM = [&](int mih, int nih, bf16x8 (*bfr)[2]) {
#pragma unroll
    for (int mi = 0; mi < 2; ++mi)
#pragma unroll
      for (int ni = 0; ni < 2; ++ni) {
        acc[mih * 2 + mi][nih * 2 + ni] =
            MFMA(af[mi][0], bfr[ni][0], acc[mih * 2 + mi][nih * 2 + ni]);
        acc[mih * 2 + mi][nih * 2 + ni] =
            MFMA(af[mi][1], bfr[ni][1], acc[mih * 2 + mi][nih * 2 + ni]);
      }
  };

  STG(0, 0); STG(0, 1); STG(0, 2); STG(0, 3);
  STG(1, 0); STG(1, 1); STG(1, 3);
  VMC(5);
  BARRIER;

  const char* A0 = smb;
  const char* A1 = smb + 16384;
  const char* B0 = smb + 32768;
  const char* B1 = smb + 65536;

  for (int it = 0; it < NIT; ++it) {
    const int t0 = 2 * it;
    const bool last = (it == NIT - 1);
    LDA(A0, 0); LDB(B0, bf01, 0); LDB(B0, bf23, 1);
    STG(t0 + 1, 2);
    VMC(6);
    BARRIER;
    __builtin_amdgcn_s_setprio(1); MM(0, 0, bf01); MM(0, 1, bf23); __builtin_amdgcn_s_setprio(0);
    BARRIER;
    LDA(A0, 1);
    STG(t0 + 2, 0); STG(t0 + 2, 1); STG(t0 + 2, 3);
    if (last) VMC(1); else VMC(6);
    BARRIER;
    __builtin_amdgcn_s_setprio(1); MM(1, 1, bf23); MM(1, 0, bf01); __builtin_amdgcn_s_setprio(0);
    BARRIER;
    LDA(A1, 0); LDB(B1, bf01, 0); LDB(B1, bf23, 1);
    STG(t0 + 2, 2);
    if (last) VMC(0); else VMC(6);
    BARRIER;
    __builtin_amdgcn_s_setprio(1); MM(0, 0, bf01); MM(0, 1, bf23); __builtin_amdgcn_s_setprio(0);
    BARRIER;
    LDA(A1, 1);
    STG(t0 + 3, 0); STG(t0 + 3, 1); STG(t0 + 3, 3);
    if (last) VMC(0); else VMC(6);
    BARRIER;
    __builtin_amdgcn_s_setprio(1); MM(1, 1, bf23); MM(1, 0, bf01); __builtin_amdgcn_s_setprio(0);
    BARRIER;
  }
#undef STG
#undef VMC

  if (EPI == 0) {
    const float qs = 0.08838834764831845f * 1.4426950408889634f;
    u16* qo = (u16*)C0;
    u16* ko = (u16*)C1;
    u16* vo = (u16*)C2;
#pragma unroll
    for (int a = 0; a < 4; ++a) {
      int s0 = m0 + wm * 64 + a * 16 + g * 4;
#pragma unroll
      for (int b = 0; b < 4; ++b) {
        int n = n0 + wn * 64 + b * 16 + lr;
        int t = n >> 11, hh = (n >> 7) & 15, d = n & 127;
        if (t == 2) {
          ushort4 pk;
          pk.x = f2bf(acc[a][b][0]);
          pk.y = f2bf(acc[a][b][1]);
          pk.z = f2bf(acc[a][b][2]);
          pk.w = f2bf(acc[a][b][3]);
          *(ushort4*)(vo + (size_t)(hh * 128 + d) * 4096 + s0) = pk;
        } else {
          float sc = (t == 0) ? qs : 1.f;
          u16* dq = (t == 0 ? qo : ko) + (size_t)(hh * 4096 + s0) * 128 + d;
#pragma unroll
          for (int j = 0; j < 4; ++j) dq[(size_t)j * 128] = f2bf(acc[a][b][j] * sc);
        }
      }
    }
  } else {
    float* C = (float*)C0;
#pragma unroll
    for (int a = 0; a < 4; ++a)
#pragma unroll
      for (int b = 0; b < 4; ++b) {
        size_t r0 = (size_t)(m0 + wm * 64 + a * 16 + g * 4);
        int cn = n0 + wn * 64 + b * 16 + lr;
#pragma unroll
        for (int j = 0; j < 4; ++j) C[(r0 + j) * N + cn] = acc[a][b][j];
      }
  }
}

// ---------------------------------------------------------------- flash attention (R14, 156us proven)
__global__ void __launch_bounds__(512)
attn_kernel(const u16* __restrict__ qg, const u16* __restrict__ kg,
            const u16* __restrict__ vtg, u16* __restrict__ og) {
  __shared__ alignas(64) char smb[131072];
  const int tid = threadIdx.x;
  const int w = tid >> 6, lane = tid & 63;
  const int ql = lane & 31, hl = lane >> 5;
  const int gb = (blockIdx.x & 7) * 32 + (blockIdx.x >> 3);  // XCD swizzle (256=8*32)
  const int h = gb >> 4;
  const int qb = gb & 15;

  const u16* ssrc[8];
  unsigned sdst[8];
  size_t sstep;
  if (w < 4) {
    sstep = 128 * 128;
#pragma unroll
    for (int i = 0; i < 8; ++i) {
      int c = w * 8 + i;
      int r = c * 4 + (lane >> 4);
      int sb = (lane & 15) ^ (r & 15);
      ssrc[i] = kg + (size_t)(h * 4096 + r) * 128 + sb * 8;
      sdst[i] = c * 1024;
    }
  } else {
    sstep = 128;
#pragma unroll
    for (int i = 0; i < 8; ++i) {
      int c = (w - 4) * 8 + i;
      int r = c * 4 + (lane >> 4);
      int sb = (lane & 15) ^ (r & 15);
      ssrc[i] = vtg + (size_t)(h * 128 + r) * 4096 + sb * 8;
      sdst[i] = 65536 + c * 1024;
    }
  }

  const u16* qrow = qg + (size_t)(h * 4096 + qb * 256 + w * 32 + ql) * 128 + hl * 8;
  bf16x8 qf[8];
#pragma unroll
  for (int s = 0; s < 8; ++s) qf[s] = *(const bf16x8*)(qrow + s * 16);

  f32x16 of[4];
#pragma unroll
  for (int i = 0; i < 4; ++i)
#pragma unroll
    for (int r = 0; r < 16; ++r) of[i][r] = 0.f;
  float mrun = -1e30f, lsum = 0.f;
  const float thr = 6.0f;

#pragma unroll
  for (int i = 0; i < 8; ++i) gload16(ssrc[i], smb + sdst[i]);

  const int kxor = (ql & 15) << 4;
  for (int t = 0; t < 32; ++t) {
    const int cur = t & 1;
    asm volatile("s_waitcnt vmcnt(0)" ::: "memory");
    __builtin_amdgcn_s_barrier();
    FENCE;
    if (t + 1 < 32) {
      const int nb = (t + 1) & 1;
#pragma unroll
      for (int i = 0; i < 8; ++i)
        gload16(ssrc[i] + (size_t)(t + 1) * sstep, smb + sdst[i] + nb * 32768);
    }
    const char* kbuf = smb + cur * 32768;
    const char* vbuf = smb + 65536 + cur * 32768;

    f32x16 st[4];
#pragma unroll
    for (int kb = 0; kb < 4; ++kb)
#pragma unroll
      for (int r = 0; r < 16; ++r) st[kb][r] = 0.f;
    __builtin_amdgcn_s_setprio(1);
#pragma unroll
    for (int s = 0; s < 8; ++s) {
      int off = ((s * 2 + hl) << 4) ^ kxor;
      bf16x8 k0 = *(const bf16x8*)(kbuf + (0 * 32 + ql) * 256 + off);
      bf16x8 k1 = *(const bf16x8*)(kbuf + (1 * 32 + ql) * 256 + off);
      bf16x8 k2 = *(const bf16x8*)(kbuf + (2 * 32 + ql) * 256 + off);
      bf16x8 k3 = *(const bf16x8*)(kbuf + (3 * 32 + ql) * 256 + off);
      st[0] = MFMA32(k0, qf[s], st[0]);
      st[1] = MFMA32(k1, qf[s], st[1]);
      st[2] = MFMA32(k2, qf[s], st[2]);
      st[3] = MFMA32(k3, qf[s], st[3]);
    }
    __builtin_amdgcn_s_setprio(0);

    float tmax = -1e30f;
#pragma unroll
    for (int kb = 0; kb < 4; ++kb)
#pragma unroll
      for (int r = 0; r < 16; ++r) tmax = fmaxf(tmax, st[kb][r]);
    tmax = fmaxf(tmax, __shfl_xor(tmax, 32));
    if (!__all(tmax - mrun <= thr)) {
      float mnew = fmaxf(mrun, tmax);
      float esc = EXP2(mrun - mnew);
#pragma unroll
      for (int db = 0; db < 4; ++db)
#pragma unroll
        for (int r = 0; r < 16; ++r) of[db][r] *= esc;
      lsum *= esc;
      mrun = mnew;
    }
    float psum = 0.f;
    union U { unsigned u[4]; bf16x8 v; };
    U paf[8];
#pragma unroll
    for (int gp = 0; gp < 2; ++gp) {
      unsigned pk0[8], pk1[8];
#pragma unroll
      for (int i = 0; i < 8; ++i) {
        float a0 = EXP2(st[2 * gp + 0][2 * i] - mrun);
        float b0 = EXP2(st[2 * gp + 0][2 * i + 1] - mrun);
        float a1 = EXP2(st[2 * gp + 1][2 * i] - mrun);
        float b1 = EXP2(st[2 * gp + 1][2 * i + 1] - mrun);
        psum += (a0 + b0) + (a1 + b1);
        pk0[i] = cvtpk(a0, b0);
        pk1[i] = cvtpk(a1, b1);
      }
      pl32swap(pk0[0], pk0[2]); pl32swap(pk0[1], pk0[3]);
      pl32swap(pk0[4], pk0[6]); pl32swap(pk0[5], pk0[7]);
      pl32swap(pk1[0], pk1[2]); pl32swap(pk1[1], pk1[3]);
      pl32swap(pk1[4], pk1[6]); pl32swap(pk1[5], pk1[7]);
#pragma unroll
      for (int i = 0; i < 4; ++i) {
        paf[gp * 4 + 0].u[i] = pk0[i];
        paf[gp * 4 + 1].u[i] = pk0[4 + i];
        paf[gp * 4 + 2].u[i] = pk1[i];
        paf[gp * 4 + 3].u[i] = pk1[4 + i];
      }
    }
    psum += __shfl_xor(psum, 32);
    lsum += psum;

    __builtin_amdgcn_s_setprio(1);
#pragma unroll
    for (int db = 0; db < 4; ++db) {
      const char* vrow = vbuf + (db * 32 + ql) * 256;
#pragma unroll
      for (int kp = 0; kp < 8; ++kp) {
        int m = (kp * 2 + hl) ^ (ql & 15);
        bf16x8 vf = *(const bf16x8*)(vrow + m * 16);
        of[db] = MFMA32(vf, paf[kp].v, of[db]);
      }
    }
    __builtin_amdgcn_s_setprio(0);
    FENCE;
  }

  float linv = 1.f / (lsum + 1e-8f);
  size_t qrow_o = (size_t)(qb * 256 + w * 32 + ql) * 2048 + h * 128;
#pragma unroll
  for (int db = 0; db < 4; ++db)
#pragma unroll
    for (int u = 0; u < 4; ++u) {
      ushort4 pk;
      pk.x = f2bf(of[db][4 * u + 0] * linv);
      pk.y = f2bf(of[db][4 * u + 1] * linv);
      pk.z = f2bf(of[db][4 * u + 2] * linv);
      pk.w = f2bf(of[db][4 * u + 3] * linv);
      *(ushort4*)(og + qrow_o + db * 32 + 8 * u + hl * 4) = pk;
    }
}

// ---------------------------------------------------------------- launcher
extern "C" void kernel_launch(void* const* d_in, const int* in_sizes, int n_in,
                              void* d_out, int out_size, void* d_ws, size_t ws_size,
                              hipStream_t stream) {
  const float* x = (const float*)d_in[0];      // [4096][2048]
  const float* w_qkv = (const float*)d_in[1];  // [6144][2048]
  const float* w_out = (const float*)d_in[2];  // [2048][2048]

  char* ws = (char*)d_ws;
  u16* xb = (u16*)(ws + 0);            // 16 MB
  u16* wqkvb = (u16*)(ws + 16777216);  // 24 MB
  u16* woutb = (u16*)(ws + 41943040);  // 8 MB
  u16* qb = (u16*)(ws + 50331648);     // 16 MB  [NH][S][HD] (pre-scaled)
  u16* kb = (u16*)(ws + 67108864);     // 16 MB  [NH][S][HD]
  u16* vtb = (u16*)(ws + 83886080);    // 16 MB  [NH][HD][S]
  u16* aob = (u16*)(ws + 100663296);   // 16 MB  [S][H]

  cast_all<<<24576, 256, 0, stream>>>(x, w_qkv, w_out, xb, wqkvb, woutb);
  gemm8<0><<<768, 512, 0, stream>>>(xb, wqkvb, qb, kb, vtb, 4096, 6144, 2048, 32);
  attn_kernel<<<256, 512, 0, stream>>>(qb, kb, vtb, aob);
  gemm8<1><<<256, 512, 0, stream>>>(aob, woutb, d_out, nullptr, nullptr, 4096, 2048, 2048, 32);
}

// Round 22
// 304.340 us; speedup vs baseline: 1.1828x; 1.0282x over previous
//
#include <hip/hip_runtime.h>
#include <stdint.h>

typedef __attribute__((ext_vector_type(4))) float f32x4;
typedef __attribute__((ext_vector_type(16))) float f32x16;
typedef __attribute__((ext_vector_type(8))) short bf16x8;
typedef unsigned short u16;

#define MFMA(a, b, c) __builtin_amdgcn_mfma_f32_16x16x32_bf16(a, b, c, 0, 0, 0)
#define MFMA32(a, b, c) __builtin_amdgcn_mfma_f32_32x32x16_bf16(a, b, c, 0, 0, 0)
#define EXP2(x) __builtin_amdgcn_exp2f(x)
#define FENCE asm volatile("" ::: "memory")
#define BARRIER do { FENCE; __builtin_amdgcn_s_barrier(); FENCE; } while (0)

__device__ __forceinline__ u16 f2bf(float f) {
  union { float f; unsigned u; } x; x.f = f;
  unsigned r = x.u + 0x7fffu + ((x.u >> 16) & 1u);
  return (u16)(r >> 16);
}

__device__ __forceinline__ unsigned cvtpk(float lo, float hi) {
  unsigned r;
  asm("v_cvt_pk_bf16_f32 %0, %1, %2" : "=v"(r) : "v"(lo), "v"(hi));
  return r;
}

__device__ __forceinline__ void pl32swap(unsigned& a, unsigned& b) {
  asm volatile("v_permlane32_swap_b32 %0, %1" : "+v"(a), "+v"(b));
}

__device__ __forceinline__ void gload16(const void* g, void* l) {
  __builtin_amdgcn_global_load_lds(
      (const __attribute__((address_space(1))) unsigned int*)g,
      (__attribute__((address_space(3))) unsigned int*)l, 16, 0, 0);
}

// ---------------------------------------------------------------- fused f32->bf16 casts (R20, correct)
__global__ void __launch_bounds__(256)
cast_all(const float* __restrict__ x, const float* __restrict__ wq,
         const float* __restrict__ wo, u16* __restrict__ xb,
         u16* __restrict__ wqb, u16* __restrict__ wob) {
  int idx = blockIdx.x * 256 + threadIdx.x;  // float4 index, 0..6291455
  const float* in;
  u16* out;
  int j;
  if (idx < 2097152) { in = x; out = xb; j = idx; }
  else if (idx < 5242880) { in = wq; out = wqb; j = idx - 2097152; }
  else { in = wo; out = wob; j = idx - 5242880; }
  float4 v = reinterpret_cast<const float4*>(in)[j];
  ushort4 o;
  o.x = f2bf(v.x); o.y = f2bf(v.y); o.z = f2bf(v.z); o.w = f2bf(v.w);
  reinterpret_cast<ushort4*>(out)[j] = o;
}

// ---------------------------------------------------------------- GEMM1: BM=128 x BN=384, 2-phase/tile
// C = A*B^T -> q/k/vt scatter. Grid 32x16 = 512 = exactly 2 rounds. 8 waves (2M x 4N),
// wave tile 64x96, acc[4][6], BK=64. 20 ds_read_b128 per 48 MFMA (2.4 ratio vs 2.0).
// LDS 128KB: A dbuf 2x16KB @0, B dbuf 2x48KB @32768. Slot-XOR (r&7) zero-conflict layout.
// Units/tile: A[2 gloads/wave, rows 0-127], B1[3, rows blk*96+0..47], B2[3, +48].
// Phases: P0{rd af(8)+bf cols0-47(6); stg B2(t+1); vmcnt; bar; 24 MFMA; bar}
//         P1{rd bf cols48-95(6); stg A,B1(t+2); vmcnt; bar; 24 MFMA; bar}
// Ledger (induction-verified): P0 drain ensures B2(t) landed: queue [B2(t)3, A/B1(t+1)5,
// B2(t+1)3]=11 -> vmcnt(8). P1 drain ensures A/B1(t+1): queue [A/B1(t+1)5, B2(t+1)3,
// A/B1(t+2)5]=13 -> vmcnt(8). Prologue: tile0 full + A/B1(1) = 13, vmcnt(8) forces
// A/B1(0). Tail: t=30 P1 -> vmcnt(3); t=31 -> vmcnt(0)/vmcnt(0). Region safety: B2(t+1)
// staged P0(t), last read P1(t-1) (barrier before); A/B1(t+2) staged P1(t), last read P0(t).
__global__ void __launch_bounds__(512)
gemm384(const u16* __restrict__ A, const u16* __restrict__ B,
        u16* __restrict__ qo, u16* __restrict__ ko, u16* __restrict__ vo, int K) {
  __shared__ alignas(16) char smb[131072];
  const int tid = threadIdx.x;
  const int w = tid >> 6, lane = tid & 63;
  const int lr = lane & 15, g = lane >> 4;
  const int wm = w >> 2, wn = w & 3;
  const int gb = (blockIdx.x & 7) * 64 + (blockIdx.x >> 3);  // XCD swizzle (512=8*64)
  const int mb = gb & 31, nb = gb >> 5;
  const int m0 = mb * 128, n0 = nb * 384;
  const int NT = K >> 6;  // 32

  const int l8 = lane >> 3, l7 = lane & 7;
  const int csb = (l7 ^ l8) * 16;  // pre-swizzled source byte col
  // A unit: 2 chunks/wave (rows 0..127)
  const char* asrc[2];
  unsigned adst[2];
#pragma unroll
  for (int j = 0; j < 2; ++j) {
    int c = 2 * w + j;
    int r = c * 8 + l8;
    asrc[j] = (const char*)(A + (size_t)(m0 + r) * K) + csb;
    adst[j] = (unsigned)(r * 128 + l7 * 16);
  }
  // B1 unit: rows blk*96+0..47; B2: +48  (3 chunks/wave each)
  const char* b1src[3];
  const char* b2src[3];
  unsigned b1dst[3], b2dst[3];
#pragma unroll
  for (int j = 0; j < 3; ++j) {
    int c = 3 * w + j;
    int blk = c / 6, sub = c % 6;
    int r1 = blk * 96 + sub * 8 + l8;
    int r2 = r1 + 48;
    b1src[j] = (const char*)(B + (size_t)(n0 + r1) * K) + csb;
    b1dst[j] = (unsigned)(r1 * 128 + l7 * 16);
    b2src[j] = (const char*)(B + (size_t)(n0 + r2) * K) + csb;
    b2dst[j] = (unsigned)(r2 * 128 + l7 * 16);
  }

#define STGA(kt)                                                        \
  do {                                                                  \
    if ((kt) < NT) {                                                    \
      size_t _ko = (size_t)(kt) * 128;                                  \
      int _da = ((kt) & 1) ? 16384 : 0;                                 \
      gload16(asrc[0] + _ko, smb + _da + adst[0]);                      \
      gload16(asrc[1] + _ko, smb + _da + adst[1]);                      \
    }                                                                   \
  } while (0)
#define STGB1(kt)                                                       \
  do {                                                                  \
    if ((kt) < NT) {                                                    \
      size_t _ko = (size_t)(kt) * 128;                                  \
      int _db = 32768 + (((kt) & 1) ? 49152 : 0);                       \
      gload16(b1src[0] + _ko, smb + _db + b1dst[0]);                    \
      gload16(b1src[1] + _ko, smb + _db + b1dst[1]);                    \
      gload16(b1src[2] + _ko, smb + _db + b1dst[2]);                    \
    }                                                                   \
  } while (0)
#define STGB2(kt)                                                       \
  do {                                                                  \
    if ((kt) < NT) {                                                    \
      size_t _ko = (size_t)(kt) * 128;                                  \
      int _db = 32768 + (((kt) & 1) ? 49152 : 0);                       \
      gload16(b2src[0] + _ko, smb + _db + b2dst[0]);                    \
      gload16(b2src[1] + _ko, smb + _db + b2dst[1]);                    \
      gload16(b2src[2] + _ko, smb + _db + b2dst[2]);                    \
    }                                                                   \
  } while (0)
#define VMC(n) asm volatile("s_waitcnt vmcnt(" #n ")" ::: "memory")

  f32x4 acc[4][6];
#pragma unroll
  for (int a = 0; a < 4; ++a)
#pragma unroll
    for (int b = 0; b < 6; ++b) acc[a][b] = f32x4{0.f, 0.f, 0.f, 0.f};
  bf16x8 af[4][2], bf[3][2];
  const int aoff0 = ((g) ^ (lr & 7)) << 4;      // ks=0 slot
  const int aoff1 = ((4 + g) ^ (lr & 7)) << 4;  // ks=1 slot
  const int arow = (wm * 64 + lr) * 128;
  const int brow = (wn * 96 + lr) * 128;

  // prologue: tile0 full + A/B1(1); drain forces A(0)+B1(0) (oldest 5 of 13)
  STGA(0); STGB1(0); STGB2(0);
  STGA(1); STGB1(1);
  VMC(8);
  BARRIER;

  for (int t = 0; t < 32; ++t) {
    const char* Ab = smb + ((t & 1) ? 16384 : 0);
    const char* Bb = smb + 32768 + ((t & 1) ? 49152 : 0);

    // ---- P0: af (all 4 row-frags) + bf cols 0-47
#pragma unroll
    for (int a = 0; a < 4; ++a) {
      const char* p = Ab + arow + a * 2048;
      af[a][0] = *(const bf16x8*)(p + aoff0);
      af[a][1] = *(const bf16x8*)(p + aoff1);
    }
#pragma unroll
    for (int nk = 0; nk < 3; ++nk) {
      const char* p = Bb + brow + nk * 2048;
      bf[nk][0] = *(const bf16x8*)(p + aoff0);
      bf[nk][1] = *(const bf16x8*)(p + aoff1);
    }
    STGB2(t + 1);
    if (t == 31) VMC(0); else VMC(8);
    BARRIER;
    __builtin_amdgcn_s_setprio(1);
#pragma unroll
    for (int a = 0; a < 4; ++a)
#pragma unroll
      for (int nk = 0; nk < 3; ++nk) {
        acc[a][nk] = MFMA(af[a][0], bf[nk][0], acc[a][nk]);
        acc[a][nk] = MFMA(af[a][1], bf[nk][1], acc[a][nk]);
      }
    __builtin_amdgcn_s_setprio(0);
    BARRIER;

    // ---- P1: bf cols 48-95 (af reused)
#pragma unroll
    for (int nk = 0; nk < 3; ++nk) {
      const char* p = Bb + brow + (48 * 128) + nk * 2048;
      bf[nk][0] = *(const bf16x8*)(p + aoff0);
      bf[nk][1] = *(const bf16x8*)(p + aoff1);
    }
    STGA(t + 2); STGB1(t + 2);
    if (t == 30) VMC(3);
    else if (t == 31) VMC(0);
    else VMC(8);
    BARRIER;
    __builtin_amdgcn_s_setprio(1);
#pragma unroll
    for (int a = 0; a < 4; ++a)
#pragma unroll
      for (int nk = 0; nk < 3; ++nk) {
        acc[a][3 + nk] = MFMA(af[a][0], bf[nk][0], acc[a][3 + nk]);
        acc[a][3 + nk] = MFMA(af[a][1], bf[nk][1], acc[a][3 + nk]);
      }
    __builtin_amdgcn_s_setprio(0);
    BARRIER;
  }
#undef STGA
#undef STGB1
#undef STGB2
#undef VMC

  // epilogue: C/D layout col = lr, row = g*4 + j; scatter q (pre-scaled), k, v^T
  const float qs = 0.08838834764831845f * 1.4426950408889634f;  // scale*log2e
#pragma unroll
  for (int a = 0; a < 4; ++a) {
    int s0 = m0 + wm * 64 + a * 16 + g * 4;
#pragma unroll
    for (int b = 0; b < 6; ++b) {
      int n = n0 + wn * 96 + b * 16 + lr;
      int t = n >> 11, hh = (n >> 7) & 15, d = n & 127;
      if (t == 2) {  // v transposed: [NH][HD][S]
        ushort4 pk;
        pk.x = f2bf(acc[a][b][0]);
        pk.y = f2bf(acc[a][b][1]);
        pk.z = f2bf(acc[a][b][2]);
        pk.w = f2bf(acc[a][b][3]);
        *(ushort4*)(vo + (size_t)(hh * 128 + d) * 4096 + s0) = pk;
      } else {
        float sc = (t == 0) ? qs : 1.f;
        u16* dq = (t == 0 ? qo : ko) + (size_t)(hh * 4096 + s0) * 128 + d;
#pragma unroll
        for (int j = 0; j < 4; ++j) dq[(size_t)j * 128] = f2bf(acc[a][b][j] * sc);
      }
    }
  }
}

// ---------------------------------------------------------------- 4-phase GEMM 128x256 (R17) for out-proj
template <int EPI>
__global__ void __launch_bounds__(512)
gemm8(const u16* __restrict__ A, const u16* __restrict__ B,
      void* __restrict__ C0, void* __restrict__ C1, void* __restrict__ C2,
      int M, int N, int K, int MBt) {
  __shared__ alignas(16) char smb[98304];
  const int tid = threadIdx.x;
  const int w = tid >> 6, lane = tid & 63;
  const int lr = lane & 15, g = lane >> 4;
  const int wm = w >> 2, wn = w & 3;
  const int gb = (blockIdx.x & 7) * ((int)gridDim.x >> 3) + (blockIdx.x >> 3);
  const int mb = gb % MBt, nb = gb / MBt;
  const int m0 = mb * 128, n0 = nb * 256;
  const int NT = K >> 6, NIT = NT >> 1;

  const int l8 = lane >> 3, l7 = lane & 7;
  const int csb = (l7 ^ l8) * 16;
  const char* asrc;
  unsigned adst;
  {
    int r = (w & 3) * 8 + ((w >> 2) << 6) + l8;
    asrc = (const char*)(A + (size_t)(m0 + r) * K) + csb;
    adst = (unsigned)(r * 128 + l7 * 16);
  }
  const char* bsrcb[2];
  unsigned bdst[2];
#pragma unroll
  for (int j = 0; j < 2; ++j) {
    int c = 2 * w + j;
    int r = (c & 3) * 8 + ((c >> 2) << 6) + l8;
    bsrcb[j] = (const char*)(B + (size_t)(n0 + r) * K) + csb;
    bdst[j] = (unsigned)(r * 128 + l7 * 16);
  }
  const size_t row32 = (size_t)32 * K * 2;

#define STG(kt, u)                                                               \
  do {                                                                           \
    if ((kt) < NT) {                                                             \
      size_t _ko = (size_t)(kt) * 128;                                           \
      int _da = ((kt) & 1) ? 16384 : 0;                                          \
      int _db = 32768 + (((kt) & 1) ? 32768 : 0);                                \
      if ((u) == 0) {                                                            \
        gload16(asrc + _ko, smb + _da + adst);                                   \
      } else if ((u) == 1) {                                                     \
        gload16(bsrcb[0] + _ko, smb + _db + bdst[0]);                            \
        gload16(bsrcb[1] + _ko, smb + _db + bdst[1]);                            \
      } else if ((u) == 2) {                                                     \
        gload16(asrc + row32 + _ko, smb + _da + 4096 + adst);                    \
      } else {                                                                   \
        gload16(bsrcb[0] + row32 + _ko, smb + _db + 4096 + bdst[0]);             \
        gload16(bsrcb[1] + row32 + _ko, smb + _db + 4096 + bdst[1]);             \
      }                                                                          \
    }                                                                            \
  } while (0)
#define VMC(n) asm volatile("s_waitcnt vmcnt(" #n ")" ::: "memory")

  f32x4 acc[4][4];
#pragma unroll
  for (int x = 0; x < 4; ++x)
#pragma unroll
    for (int y = 0; y < 4; ++y) acc[x][y] = f32x4{0.f, 0.f, 0.f, 0.f};
  bf16x8 af[2][2], bf01[2][2], bf23[2][2];
  const int aoff0 = ((g) ^ (lr & 7)) << 4;
  const int aoff1 = ((4 + g) ^ (lr & 7)) << 4;
  const int arowb = (wm * 64 + lr) * 128;
  const int browb = (wn * 64 + lr) * 128;

  auto LDA = [&](const char* base, int mih) {
#pragma unroll
    for (int mi = 0; mi < 2; ++mi) {
      const char* p = base + arowb + (mih * 32 + mi * 16) * 128;
      af[mi][0] = *(const bf16x8*)(p + aoff0);
      af[mi][1] = *(const bf16x8*)(p + aoff1);
    }
  };
  auto LDB = [&](const char* base, bf16x8 (*bfr)[2], int nih) {
#pragma unroll
    for (int ni = 0; ni < 2; ++ni) {
      const char* p = base + browb + (nih * 32 + ni * 16) * 128;
      bfr[ni][0] = *(const bf16x8*)(p + aoff0);
      bfr[ni][1] = *(const bf16x8*)(p + aoff1);
    }
  };
  auto MM = [&](int mih, int nih, bf16x8 (*bfr)[2]) {
#pragma unroll
    for (int mi = 0; mi < 2; ++mi)
#pragma unroll
      for (int ni = 0; ni < 2; ++ni) {
        acc[mih * 2 + mi][nih * 2 + ni] =
            MFMA(af[mi][0], bfr[ni][0], acc[mih * 2 + mi][nih * 2 + ni]);
        acc[mih * 2 + mi][nih * 2 + ni] =
            MFMA(af[mi][1], bfr[ni][1], acc[mih * 2 + mi][nih * 2 + ni]);
      }
  };

  STG(0, 0); STG(0, 1); STG(0, 2); STG(0, 3);
  STG(1, 0); STG(1, 1); STG(1, 3);
  VMC(5);
  BARRIER;

  const char* A0 = smb;
  const char* A1 = smb + 16384;
  const char* B0 = smb + 32768;
  const char* B1 = smb + 65536;

  for (int it = 0; it < NIT; ++it) {
    const int t0 = 2 * it;
    const bool last = (it == NIT - 1);
    LDA(A0, 0); LDB(B0, bf01, 0); LDB(B0, bf23, 1);
    STG(t0 + 1, 2);
    VMC(6);
    BARRIER;
    __builtin_amdgcn_s_setprio(1); MM(0, 0, bf01); MM(0, 1, bf23); __builtin_amdgcn_s_setprio(0);
    BARRIER;
    LDA(A0, 1);
    STG(t0 + 2, 0); STG(t0 + 2, 1); STG(t0 + 2, 3);
    if (last) VMC(1); else VMC(6);
    BARRIER;
    __builtin_amdgcn_s_setprio(1); MM(1, 1, bf23); MM(1, 0, bf01); __builtin_amdgcn_s_setprio(0);
    BARRIER;
    LDA(A1, 0); LDB(B1, bf01, 0); LDB(B1, bf23, 1);
    STG(t0 + 2, 2);
    if (last) VMC(0); else VMC(6);
    BARRIER;
    __builtin_amdgcn_s_setprio(1); MM(0, 0, bf01); MM(0, 1, bf23); __builtin_amdgcn_s_setprio(0);
    BARRIER;
    LDA(A1, 1);
    STG(t0 + 3, 0); STG(t0 + 3, 1); STG(t0 + 3, 3);
    if (last) VMC(0); else VMC(6);
    BARRIER;
    __builtin_amdgcn_s_setprio(1); MM(1, 1, bf23); MM(1, 0, bf01); __builtin_amdgcn_s_setprio(0);
    BARRIER;
  }
#undef STG
#undef VMC

  float* C = (float*)C0;
#pragma unroll
  for (int a = 0; a < 4; ++a)
#pragma unroll
    for (int b = 0; b < 4; ++b) {
      size_t r0 = (size_t)(m0 + wm * 64 + a * 16 + g * 4);
      int cn = n0 + wn * 64 + b * 16 + lr;
#pragma unroll
      for (int j = 0; j < 4; ++j) C[(r0 + j) * N + cn] = acc[a][b][j];
    }
}

// ---------------------------------------------------------------- flash attention (R14, 156us proven)
__global__ void __launch_bounds__(512)
attn_kernel(const u16* __restrict__ qg, const u16* __restrict__ kg,
            const u16* __restrict__ vtg, u16* __restrict__ og) {
  __shared__ alignas(64) char smb[131072];
  const int tid = threadIdx.x;
  const int w = tid >> 6, lane = tid & 63;
  const int ql = lane & 31, hl = lane >> 5;
  const int gb = (blockIdx.x & 7) * 32 + (blockIdx.x >> 3);  // XCD swizzle (256=8*32)
  const int h = gb >> 4;
  const int qb = gb & 15;

  const u16* ssrc[8];
  unsigned sdst[8];
  size_t sstep;
  if (w < 4) {
    sstep = 128 * 128;
#pragma unroll
    for (int i = 0; i < 8; ++i) {
      int c = w * 8 + i;
      int r = c * 4 + (lane >> 4);
      int sb = (lane & 15) ^ (r & 15);
      ssrc[i] = kg + (size_t)(h * 4096 + r) * 128 + sb * 8;
      sdst[i] = c * 1024;
    }
  } else {
    sstep = 128;
#pragma unroll
    for (int i = 0; i < 8; ++i) {
      int c = (w - 4) * 8 + i;
      int r = c * 4 + (lane >> 4);
      int sb = (lane & 15) ^ (r & 15);
      ssrc[i] = vtg + (size_t)(h * 128 + r) * 4096 + sb * 8;
      sdst[i] = 65536 + c * 1024;
    }
  }

  const u16* qrow = qg + (size_t)(h * 4096 + qb * 256 + w * 32 + ql) * 128 + hl * 8;
  bf16x8 qf[8];
#pragma unroll
  for (int s = 0; s < 8; ++s) qf[s] = *(const bf16x8*)(qrow + s * 16);

  f32x16 of[4];
#pragma unroll
  for (int i = 0; i < 4; ++i)
#pragma unroll
    for (int r = 0; r < 16; ++r) of[i][r] = 0.f;
  float mrun = -1e30f, lsum = 0.f;
  const float thr = 6.0f;

#pragma unroll
  for (int i = 0; i < 8; ++i) gload16(ssrc[i], smb + sdst[i]);

  const int kxor = (ql & 15) << 4;
  for (int t = 0; t < 32; ++t) {
    const int cur = t & 1;
    asm volatile("s_waitcnt vmcnt(0)" ::: "memory");
    __builtin_amdgcn_s_barrier();
    FENCE;
    if (t + 1 < 32) {
      const int nb = (t + 1) & 1;
#pragma unroll
      for (int i = 0; i < 8; ++i)
        gload16(ssrc[i] + (size_t)(t + 1) * sstep, smb + sdst[i] + nb * 32768);
    }
    const char* kbuf = smb + cur * 32768;
    const char* vbuf = smb + 65536 + cur * 32768;

    f32x16 st[4];
#pragma unroll
    for (int kb = 0; kb < 4; ++kb)
#pragma unroll
      for (int r = 0; r < 16; ++r) st[kb][r] = 0.f;
    __builtin_amdgcn_s_setprio(1);
#pragma unroll
    for (int s = 0; s < 8; ++s) {
      int off = ((s * 2 + hl) << 4) ^ kxor;
      bf16x8 k0 = *(const bf16x8*)(kbuf + (0 * 32 + ql) * 256 + off);
      bf16x8 k1 = *(const bf16x8*)(kbuf + (1 * 32 + ql) * 256 + off);
      bf16x8 k2 = *(const bf16x8*)(kbuf + (2 * 32 + ql) * 256 + off);
      bf16x8 k3 = *(const bf16x8*)(kbuf + (3 * 32 + ql) * 256 + off);
      st[0] = MFMA32(k0, qf[s], st[0]);
      st[1] = MFMA32(k1, qf[s], st[1]);
      st[2] = MFMA32(k2, qf[s], st[2]);
      st[3] = MFMA32(k3, qf[s], st[3]);
    }
    __builtin_amdgcn_s_setprio(0);

    float tmax = -1e30f;
#pragma unroll
    for (int kb = 0; kb < 4; ++kb)
#pragma unroll
      for (int r = 0; r < 16; ++r) tmax = fmaxf(tmax, st[kb][r]);
    tmax = fmaxf(tmax, __shfl_xor(tmax, 32));
    if (!__all(tmax - mrun <= thr)) {
      float mnew = fmaxf(mrun, tmax);
      float esc = EXP2(mrun - mnew);
#pragma unroll
      for (int db = 0; db < 4; ++db)
#pragma unroll
        for (int r = 0; r < 16; ++r) of[db][r] *= esc;
      lsum *= esc;
      mrun = mnew;
    }
    float psum = 0.f;
    union U { unsigned u[4]; bf16x8 v; };
    U paf[8];
#pragma unroll
    for (int gp = 0; gp < 2; ++gp) {
      unsigned pk0[8], pk1[8];
#pragma unroll
      for (int i = 0; i < 8; ++i) {
        float a0 = EXP2(st[2 * gp + 0][2 * i] - mrun);
        float b0 = EXP2(st[2 * gp + 0][2 * i + 1] - mrun);
        float a1 = EXP2(st[2 * gp + 1][2 * i] - mrun);
        float b1 = EXP2(st[2 * gp + 1][2 * i + 1] - mrun);
        psum += (a0 + b0) + (a1 + b1);
        pk0[i] = cvtpk(a0, b0);
        pk1[i] = cvtpk(a1, b1);
      }
      pl32swap(pk0[0], pk0[2]); pl32swap(pk0[1], pk0[3]);
      pl32swap(pk0[4], pk0[6]); pl32swap(pk0[5], pk0[7]);
      pl32swap(pk1[0], pk1[2]); pl32swap(pk1[1], pk1[3]);
      pl32swap(pk1[4], pk1[6]); pl32swap(pk1[5], pk1[7]);
#pragma unroll
      for (int i = 0; i < 4; ++i) {
        paf[gp * 4 + 0].u[i] = pk0[i];
        paf[gp * 4 + 1].u[i] = pk0[4 + i];
        paf[gp * 4 + 2].u[i] = pk1[i];
        paf[gp * 4 + 3].u[i] = pk1[4 + i];
      }
    }
    psum += __shfl_xor(psum, 32);
    lsum += psum;

    __builtin_amdgcn_s_setprio(1);
#pragma unroll
    for (int db = 0; db < 4; ++db) {
      const char* vrow = vbuf + (db * 32 + ql) * 256;
#pragma unroll
      for (int kp = 0; kp < 8; ++kp) {
        int m = (kp * 2 + hl) ^ (ql & 15);
        bf16x8 vf = *(const bf16x8*)(vrow + m * 16);
        of[db] = MFMA32(vf, paf[kp].v, of[db]);
      }
    }
    __builtin_amdgcn_s_setprio(0);
    FENCE;
  }

  float linv = 1.f / (lsum + 1e-8f);
  size_t qrow_o = (size_t)(qb * 256 + w * 32 + ql) * 2048 + h * 128;
#pragma unroll
  for (int db = 0; db < 4; ++db)
#pragma unroll
    for (int u = 0; u < 4; ++u) {
      ushort4 pk;
      pk.x = f2bf(of[db][4 * u + 0] * linv);
      pk.y = f2bf(of[db][4 * u + 1] * linv);
      pk.z = f2bf(of[db][4 * u + 2] * linv);
      pk.w = f2bf(of[db][4 * u + 3] * linv);
      *(ushort4*)(og + qrow_o + db * 32 + 8 * u + hl * 4) = pk;
    }
}

// ---------------------------------------------------------------- launcher
extern "C" void kernel_launch(void* const* d_in, const int* in_sizes, int n_in,
                              void* d_out, int out_size, void* d_ws, size_t ws_size,
                              hipStream_t stream) {
  const float* x = (const float*)d_in[0];      // [4096][2048]
  const float* w_qkv = (const float*)d_in[1];  // [6144][2048]
  const float* w_out = (const float*)d_in[2];  // [2048][2048]

  char* ws = (char*)d_ws;
  u16* xb = (u16*)(ws + 0);            // 16 MB
  u16* wqkvb = (u16*)(ws + 16777216);  // 24 MB
  u16* woutb = (u16*)(ws + 41943040);  // 8 MB
  u16* qb = (u16*)(ws + 50331648);     // 16 MB  [NH][S][HD] (pre-scaled)
  u16* kb = (u16*)(ws + 67108864);     // 16 MB  [NH][S][HD]
  u16* vtb = (u16*)(ws + 83886080);    // 16 MB  [NH][HD][S]
  u16* aob = (u16*)(ws + 100663296);   // 16 MB  [S][H]

  cast_all<<<24576, 256, 0, stream>>>(x, w_qkv, w_out, xb, wqkvb, woutb);
  gemm384<<<512, 512, 0, stream>>>(xb, wqkvb, qb, kb, vtb, 2048);
  attn_kernel<<<256, 512, 0, stream>>>(qb, kb, vtb, aob);
  gemm8<1><<<256, 512, 0, stream>>>(aob, woutb, d_out, nullptr, nullptr, 4096, 2048, 2048, 32);
}